// Round 1
// baseline (16264.009 us; speedup 1.0000x reference)
//
#include <hip/hip_runtime.h>
#include <hip/hip_bf16.h>
#include <stdint.h>

#define BATCH 4
#define SEQ 1024
#define DIMX 1024
#define VOCAB 32000
#define NLAYERS 4
#define TCH 16      // chunk length
#define CCH 64      // number of chunks (TCH*CCH == SEQ)

using bf16x8 = __attribute__((ext_vector_type(8))) short;
using f32x4v = __attribute__((ext_vector_type(4))) float;

// ---------------- embedding gather: H[(t*B+b)*D + d] = embed[ids[b][t]][d]
__global__ __launch_bounds__(256) void k_embed(const int* __restrict__ ids,
                                               const float* __restrict__ emb,
                                               float* __restrict__ H) {
  int idx = blockIdx.x * 256 + threadIdx.x;   // over SEQ*BATCH*DIMX/4 float4s
  int d4 = idx & (DIMX / 4 - 1);
  int tb = idx >> 8;
  int t = tb >> 2, b = tb & 3;
  int id = ids[b * SEQ + t];
  float4 v = reinterpret_cast<const float4*>(emb + (size_t)id * DIMX)[d4];
  reinterpret_cast<float4*>(H)[idx] = v;
}

// ---------------- generic strided row copy (row r -> (r>>2)*cs + (r&3)*bs)
__global__ __launch_bounds__(256) void k_copy_rows(const float* __restrict__ src, int s_cs, int s_bs,
                                                   float* __restrict__ dst, int d_cs, int d_bs,
                                                   int rows, int cols4) {
  int idx = blockIdx.x * 256 + threadIdx.x;
  int c4 = idx % cols4;
  int r = idx / cols4;
  if (r >= rows) return;
  const float4* s = reinterpret_cast<const float4*>(src + (size_t)(r >> 2) * s_cs + (size_t)(r & 3) * s_bs);
  float4* d = reinterpret_cast<float4*>(dst + (size_t)(r >> 2) * d_cs + (size_t)(r & 3) * d_bs);
  d[c4] = s[c4];
}

// ---------------- fp32 GEMM, 64x64 tile, 4x4 micro-tile.
// OUT1[m][n] = dot(m,n) + ADD[m][n];  OUT2[m][n] = dot(m,n)  (optional)
// Row offset of any operand: base + (m>>2)*cs + (m&3)*bs   (col n contiguous)
// NT: B operand is Bt[n*ldb + k]; NN: B[k*ldb + n]
template <bool NT>
__global__ __launch_bounds__(256) void k_gemm64(
    int M, int N, int K,
    const float* __restrict__ Ab, int a_cs, int a_bs,
    const float* __restrict__ Bb, int ldb,
    const float* __restrict__ ADDb, int add_cs, int add_bs,
    float* __restrict__ O1, int o1_cs, int o1_bs,
    float* __restrict__ O2, int o2_cs, int o2_bs) {
  __shared__ float As[16][68];
  __shared__ float Bs[16][68];
  int tid = threadIdx.x;
  int n0 = blockIdx.x * 64, m0 = blockIdx.y * 64;
  int tx = tid & 15, ty = tid >> 4;
  float acc[4][4] = {};
  for (int kt = 0; kt < K; kt += 16) {
    {
      int mm = tid >> 2, kc = (tid & 3) * 4;
      int m = m0 + mm;
      float4 av = make_float4(0.f, 0.f, 0.f, 0.f);
      if (m < M) av = *reinterpret_cast<const float4*>(Ab + (size_t)(m >> 2) * a_cs + (size_t)(m & 3) * a_bs + kt + kc);
      As[kc + 0][mm] = av.x; As[kc + 1][mm] = av.y; As[kc + 2][mm] = av.z; As[kc + 3][mm] = av.w;
      if (NT) {
        int n = n0 + mm;
        float4 bv = *reinterpret_cast<const float4*>(Bb + (size_t)n * ldb + kt + kc);
        Bs[kc + 0][mm] = bv.x; Bs[kc + 1][mm] = bv.y; Bs[kc + 2][mm] = bv.z; Bs[kc + 3][mm] = bv.w;
      } else {
        int kk = tid >> 4, nc = (tid & 15) * 4;
        float4 bv = *reinterpret_cast<const float4*>(Bb + (size_t)(kt + kk) * ldb + n0 + nc);
        *reinterpret_cast<float4*>(&Bs[kk][nc]) = bv;
      }
    }
    __syncthreads();
#pragma unroll
    for (int kk = 0; kk < 16; ++kk) {
      float4 a = *reinterpret_cast<const float4*>(&As[kk][ty * 4]);
      float4 b = *reinterpret_cast<const float4*>(&Bs[kk][tx * 4]);
      float aa[4] = {a.x, a.y, a.z, a.w};
      float bb[4] = {b.x, b.y, b.z, b.w};
#pragma unroll
      for (int i = 0; i < 4; ++i)
#pragma unroll
        for (int j = 0; j < 4; ++j) acc[i][j] = fmaf(aa[i], bb[j], acc[i][j]);
    }
    __syncthreads();
  }
#pragma unroll
  for (int i = 0; i < 4; ++i) {
    int m = m0 + ty * 4 + i;
    if (m >= M) continue;
#pragma unroll
    for (int j = 0; j < 4; ++j) {
      int n = n0 + tx * 4 + j;
      float dot = acc[i][j];
      float v = dot;
      if (ADDb) v += ADDb[(size_t)(m >> 2) * add_cs + (size_t)(m & 3) * add_bs + n];
      O1[(size_t)(m >> 2) * o1_cs + (size_t)(m & 3) * o1_bs + n] = v;
      if (O2) O2[(size_t)(m >> 2) * o2_cs + (size_t)(m & 3) * o2_bs + n] = dot;
    }
  }
}

// ---------------- fp32 GEMM, 32x32 tile (for small-M scan steps: more blocks in flight)
template <bool NT>
__global__ __launch_bounds__(256) void k_gemm32(
    int M, int N, int K,
    const float* __restrict__ Ab, int a_cs, int a_bs,
    const float* __restrict__ Bb, int ldb,
    const float* __restrict__ ADDb, int add_cs, int add_bs,
    float* __restrict__ O1, int o1_cs, int o1_bs,
    float* __restrict__ O2, int o2_cs, int o2_bs) {
  __shared__ float As[16][36];
  __shared__ float Bs[16][36];
  int tid = threadIdx.x;
  int n0 = blockIdx.x * 32, m0 = blockIdx.y * 32;
  int tx = tid & 15, ty = tid >> 4;
  float acc[2][2] = {};
  for (int kt = 0; kt < K; kt += 16) {
    {
      int mm = tid >> 3, kc = (tid & 7) * 2;
      int m = m0 + mm;
      float2 av = make_float2(0.f, 0.f);
      if (m < M) av = *reinterpret_cast<const float2*>(Ab + (size_t)(m >> 2) * a_cs + (size_t)(m & 3) * a_bs + kt + kc);
      As[kc + 0][mm] = av.x; As[kc + 1][mm] = av.y;
      if (NT) {
        int n = n0 + mm;
        float2 bv = *reinterpret_cast<const float2*>(Bb + (size_t)n * ldb + kt + kc);
        Bs[kc + 0][mm] = bv.x; Bs[kc + 1][mm] = bv.y;
      } else {
        int kk = tid >> 4, nc = (tid & 15) * 2;
        float2 bv = *reinterpret_cast<const float2*>(Bb + (size_t)(kt + kk) * ldb + n0 + nc);
        *reinterpret_cast<float2*>(&Bs[kk][nc]) = bv;
      }
    }
    __syncthreads();
#pragma unroll
    for (int kk = 0; kk < 16; ++kk) {
      float2 a = *reinterpret_cast<const float2*>(&As[kk][ty * 2]);
      float2 b = *reinterpret_cast<const float2*>(&Bs[kk][tx * 2]);
      acc[0][0] = fmaf(a.x, b.x, acc[0][0]);
      acc[0][1] = fmaf(a.x, b.y, acc[0][1]);
      acc[1][0] = fmaf(a.y, b.x, acc[1][0]);
      acc[1][1] = fmaf(a.y, b.y, acc[1][1]);
    }
    __syncthreads();
  }
#pragma unroll
  for (int i = 0; i < 2; ++i) {
    int m = m0 + ty * 2 + i;
    if (m >= M) continue;
#pragma unroll
    for (int j = 0; j < 2; ++j) {
      int n = n0 + tx * 2 + j;
      float dot = acc[i][j];
      float v = dot;
      if (ADDb) v += ADDb[(size_t)(m >> 2) * add_cs + (size_t)(m & 3) * add_bs + n];
      O1[(size_t)(m >> 2) * o1_cs + (size_t)(m & 3) * o1_bs + n] = v;
      if (O2) O2[(size_t)(m >> 2) * o2_cs + (size_t)(m & 3) * o2_bs + n] = dot;
    }
  }
}

// ---------------- casts to bf16
__device__ __forceinline__ uint16_t f2b(float f) {
  __hip_bfloat16 h = __float2bfloat16(f);
  return *reinterpret_cast<uint16_t*>(&h);
}

// ys: H[(t*B+b)*D+d] -> Y[(b*L+t)*D+d]  (does the l,b -> b,l reindex for 'blv')
__global__ __launch_bounds__(256) void k_cast_ys(const float* __restrict__ Hsrc, uint16_t* __restrict__ Y) {
  int idx = blockIdx.x * 256 + threadIdx.x;
  int d4 = idx & (DIMX / 4 - 1);
  int tb = idx >> 8;
  int t = tb >> 2, b = tb & 3;
  float4 v = reinterpret_cast<const float4*>(Hsrc)[idx];
  ushort4 o;
  o.x = f2b(v.x); o.y = f2b(v.y); o.z = f2b(v.z); o.w = f2b(v.w);
  reinterpret_cast<ushort4*>(Y + (size_t)(b * SEQ + t) * DIMX)[d4] = o;
}

__global__ __launch_bounds__(256) void k_cast_w(const float* __restrict__ src, uint16_t* __restrict__ dst, int n4) {
  int idx = blockIdx.x * 256 + threadIdx.x;
  if (idx >= n4) return;
  float4 v = reinterpret_cast<const float4*>(src)[idx];
  ushort4 o;
  o.x = f2b(v.x); o.y = f2b(v.y); o.z = f2b(v.z); o.w = f2b(v.w);
  reinterpret_cast<ushort4*>(dst)[idx] = o;
}

// ---------------- logits GEMM: C[m][v] = sum_d A[m][d]*Bt[v][d], bf16 MFMA, 128x128 tile
__global__ __launch_bounds__(256) void k_logits(const uint16_t* __restrict__ A,
                                                const uint16_t* __restrict__ Bt,
                                                float* __restrict__ C) {
  __shared__ uint16_t As[128 * 32];
  __shared__ uint16_t Bs[128 * 32];
  int tid = threadIdx.x;
  int bx = blockIdx.x, by = blockIdx.y;
  int lane = tid & 63, wave = tid >> 6;
  int wm = wave >> 1, wn = wave & 1;
  f32x4v acc[4][4] = {};
  const uint16_t* Ag = A + (size_t)by * 128 * 1024;
  const uint16_t* Bg = Bt + (size_t)bx * 128 * 1024;
  for (int kt = 0; kt < 1024; kt += 32) {
    __syncthreads();
#pragma unroll
    for (int q = 0; q < 2; ++q) {
      int off = q * 4096 + tid * 16;             // byte offset within 8KB tile
      int r = off >> 6, cu = (off & 63) >> 1;    // row, col (ushort units)
      __builtin_amdgcn_global_load_lds(
          (__attribute__((address_space(1))) uint32_t*)(Ag + (size_t)r * 1024 + kt + cu),
          (__attribute__((address_space(3))) uint32_t*)((char*)As + off), 16, 0, 0);
      __builtin_amdgcn_global_load_lds(
          (__attribute__((address_space(1))) uint32_t*)(Bg + (size_t)r * 1024 + kt + cu),
          (__attribute__((address_space(3))) uint32_t*)((char*)Bs + off), 16, 0, 0);
    }
    __syncthreads();
    int rsel = lane & 15, ko = (lane >> 4) * 8;
    bf16x8 af[4], bfr[4];
#pragma unroll
    for (int mf = 0; mf < 4; ++mf)
      af[mf] = *reinterpret_cast<const bf16x8*>(As + (wm * 64 + mf * 16 + rsel) * 32 + ko);
#pragma unroll
    for (int nf = 0; nf < 4; ++nf)
      bfr[nf] = *reinterpret_cast<const bf16x8*>(Bs + (wn * 64 + nf * 16 + rsel) * 32 + ko);
#pragma unroll
    for (int mf = 0; mf < 4; ++mf)
#pragma unroll
      for (int nf = 0; nf < 4; ++nf)
        acc[mf][nf] = __builtin_amdgcn_mfma_f32_16x16x32_bf16(af[mf], bfr[nf], acc[mf][nf], 0, 0, 0);
  }
  int rowg = (lane >> 4) * 4;
  int colg = lane & 15;
#pragma unroll
  for (int mf = 0; mf < 4; ++mf)
#pragma unroll
    for (int nf = 0; nf < 4; ++nf)
#pragma unroll
      for (int r = 0; r < 4; ++r) {
        int m = by * 128 + wm * 64 + mf * 16 + rowg + r;
        int n = bx * 128 + wn * 64 + nf * 16 + colg;
        C[(size_t)m * VOCAB + n] = acc[mf][nf][r];
      }
}

// =========================================================================
extern "C" void kernel_launch(void* const* d_in, const int* in_sizes, int n_in,
                              void* d_out, int out_size, void* d_ws, size_t ws_size,
                              hipStream_t stream) {
  const int* ids = (const int*)d_in[0];
  const float* emb = (const float*)d_in[1];
  const float* W = (const float*)d_in[2];
  const float* outw = (const float*)d_in[3];
  const float* starter = (const float*)d_in[4];
  float* out = (float*)d_out;

  char* wsb = (char*)d_ws;
  size_t off = 0;
  auto alloc = [&](size_t bytes) {
    void* p = wsb + off;
    off = (off + bytes + 255) & ~(size_t)255;
    return p;
  };
  float* H0 = (float*)alloc((size_t)SEQ * BATCH * DIMX * 4);
  float* H1 = (float*)alloc((size_t)SEQ * BATCH * DIMX * 4);
  float* P = (float*)alloc((size_t)SEQ * BATCH * 2 * DIMX * 4);  // [t][b][a(0:1024)|u(1024:2048)]
  float* S = (float*)alloc((size_t)SEQ * BATCH * DIMX * 4);      // S[t] = s_{t-1}
  float* SIG = (float*)alloc((size_t)(CCH + 1) * BATCH * DIMX * 4);
  float* G0 = (float*)alloc((size_t)CCH * BATCH * DIMX * 4);
  float* G1 = (float*)alloc((size_t)CCH * BATCH * DIMX * 4);
  float* Ass = (float*)alloc((size_t)DIMX * DIMX * 4);
  float* Pw0 = (float*)alloc((size_t)DIMX * DIMX * 4);
  float* Pw1 = (float*)alloc((size_t)DIMX * DIMX * 4);
  uint16_t* YSB = (uint16_t*)alloc((size_t)SEQ * BATCH * DIMX * 2);
  uint16_t* OWB = (uint16_t*)alloc((size_t)VOCAB * DIMX * 2);

  k_embed<<<SEQ * BATCH * DIMX / 4 / 256, 256, 0, stream>>>(ids, emb, H0);

  float* Hc = H0;
  float* Hn = H1;
  float* Pu = P + DIMX;  // u half

  for (int l = 0; l < NLAYERS; ++l) {
    const float* Wl = W + (size_t)l * 2 * DIMX * 2 * DIMX;

    // a,u = H @ W[:, 0:1024]^T   (N=2048: rows 0..1023 -> a, 1024..2047 -> u)
    k_gemm64<true><<<dim3(2 * DIMX / 64, SEQ * BATCH / 64), 256, 0, stream>>>(
        SEQ * BATCH, 2 * DIMX, DIMX,
        Hc, 4 * DIMX, DIMX,
        Wl, 2 * DIMX,
        nullptr, 0, 0,
        P, 4 * 2 * DIMX, 2 * DIMX,
        nullptr, 0, 0);

    // dense copy of W_ss = W[1024+i][1024+j]
    k_copy_rows<<<DIMX * DIMX / 4 / 256, 256, 0, stream>>>(
        Wl + (size_t)DIMX * 2 * DIMX + DIMX, 4 * 2 * DIMX, 2 * DIMX,
        Ass, 4 * DIMX, DIMX, DIMX, DIMX / 4);

    // A^16 via 4 squarings (fp32)
    k_gemm64<false><<<dim3(16, 16), 256, 0, stream>>>(DIMX, DIMX, DIMX, Ass, 4 * DIMX, DIMX, Ass, DIMX,
                                                      nullptr, 0, 0, Pw0, 4 * DIMX, DIMX, nullptr, 0, 0);
    k_gemm64<false><<<dim3(16, 16), 256, 0, stream>>>(DIMX, DIMX, DIMX, Pw0, 4 * DIMX, DIMX, Pw0, DIMX,
                                                      nullptr, 0, 0, Pw1, 4 * DIMX, DIMX, nullptr, 0, 0);
    k_gemm64<false><<<dim3(16, 16), 256, 0, stream>>>(DIMX, DIMX, DIMX, Pw1, 4 * DIMX, DIMX, Pw1, DIMX,
                                                      nullptr, 0, 0, Pw0, 4 * DIMX, DIMX, nullptr, 0, 0);
    k_gemm64<false><<<dim3(16, 16), 256, 0, stream>>>(DIMX, DIMX, DIMX, Pw0, 4 * DIMX, DIMX, Pw0, DIMX,
                                                      nullptr, 0, 0, Pw1, 4 * DIMX, DIMX, nullptr, 0, 0);
    float* A16 = Pw1;

    // phase 1: local scans l_t = A*l_{t-1} + u_t (in place over u); j=0 is identity
    for (int j = 1; j < TCH; ++j) {
      k_gemm32<true><<<dim3(DIMX / 32, CCH * BATCH / 32), 256, 0, stream>>>(
          CCH * BATCH, DIMX, DIMX,
          Pu + (size_t)(j - 1) * BATCH * 2 * DIMX, TCH * BATCH * 2 * DIMX, 2 * DIMX,
          Ass, DIMX,
          Pu + (size_t)j * BATCH * 2 * DIMX, TCH * BATCH * 2 * DIMX, 2 * DIMX,
          Pu + (size_t)j * BATCH * 2 * DIMX, TCH * BATCH * 2 * DIMX, 2 * DIMX,
          nullptr, 0, 0);
    }

    // sigma_0 = starter[l] broadcast over batch
    k_copy_rows<<<BATCH * DIMX / 4 / 256, 256, 0, stream>>>(starter + (size_t)l * DIMX, 0, 0,
                                                            SIG, 4 * DIMX, DIMX, BATCH, DIMX / 4);
    // phase 2: sigma_{c+1} = A^16 sigma_c + l_end(c)
    for (int c = 0; c < CCH; ++c) {
      k_gemm32<true><<<dim3(DIMX / 32, 1), 256, 0, stream>>>(
          BATCH, DIMX, DIMX,
          SIG + (size_t)c * BATCH * DIMX, 4 * DIMX, DIMX,
          A16, DIMX,
          Pu + (size_t)(c * TCH + TCH - 1) * BATCH * 2 * DIMX, 0, 2 * DIMX,
          SIG + (size_t)(c + 1) * BATCH * DIMX, 4 * DIMX, DIMX,
          nullptr, 0, 0);
    }

    // phase 3 init: G = sigma_c ; S[c*T] = sigma_c
    k_copy_rows<<<CCH * BATCH * DIMX / 4 / 256, 256, 0, stream>>>(SIG, 4 * DIMX, DIMX, G0, 4 * DIMX, DIMX,
                                                                  CCH * BATCH, DIMX / 4);
    k_copy_rows<<<CCH * BATCH * DIMX / 4 / 256, 256, 0, stream>>>(SIG, 4 * DIMX, DIMX, S, TCH * BATCH * DIMX, DIMX,
                                                                  CCH * BATCH, DIMX / 4);
    // phase 3: G_j = A G_{j-1};  S[cT+j] = G_j + l_{cT+j-1}
    float* Gp = G0;
    float* Gq = G1;
    for (int j = 1; j < TCH; ++j) {
      k_gemm32<true><<<dim3(DIMX / 32, CCH * BATCH / 32), 256, 0, stream>>>(
          CCH * BATCH, DIMX, DIMX,
          Gp, 4 * DIMX, DIMX,
          Ass, DIMX,
          Pu + (size_t)(j - 1) * BATCH * 2 * DIMX, TCH * BATCH * 2 * DIMX, 2 * DIMX,
          S + (size_t)j * BATCH * DIMX, TCH * BATCH * DIMX, DIMX,
          Gq, 4 * DIMX, DIMX);
      float* tmp = Gp; Gp = Gq; Gq = tmp;
    }

    // H_next = a + S @ W_hs^T
    k_gemm64<true><<<dim3(DIMX / 64, SEQ * BATCH / 64), 256, 0, stream>>>(
        SEQ * BATCH, DIMX, DIMX,
        S, 4 * DIMX, DIMX,
        Wl + DIMX, 2 * DIMX,
        P, 4 * 2 * DIMX, 2 * DIMX,
        Hn, 4 * DIMX, DIMX,
        nullptr, 0, 0);

    float* tmp = Hc; Hc = Hn; Hn = tmp;
  }

  // logits = ys @ out_w^T in bf16 MFMA, f32 out
  k_cast_ys<<<SEQ * BATCH * DIMX / 4 / 256, 256, 0, stream>>>(Hc, YSB);
  k_cast_w<<<(int)((size_t)VOCAB * DIMX / 4 / 256), 256, 0, stream>>>(outw, OWB, VOCAB * DIMX / 4);
  k_logits<<<dim3(VOCAB / 128, SEQ * BATCH / 128), 256, 0, stream>>>(YSB, OWB, out);
}

// Round 2
// 8513.314 us; speedup vs baseline: 1.9104x; 1.9104x over previous
//
#include <hip/hip_runtime.h>
#include <hip/hip_bf16.h>
#include <stdint.h>

#define BATCH 4
#define SEQ 1024
#define DIMX 1024
#define VOCAB 32000
#define NLAYERS 4
#define TCH 16      // outer chunk length
#define CCH 64      // outer chunk count
#define TC2 8       // inner (phase-2) chunk length
#define CC2 8       // inner chunk count

using bf16x8 = __attribute__((ext_vector_type(8))) short;
using f32x4v = __attribute__((ext_vector_type(4))) float;

__device__ __forceinline__ uint16_t f2b(float f) {
  __hip_bfloat16 h = __float2bfloat16(f);
  return *reinterpret_cast<uint16_t*>(&h);
}
__device__ __forceinline__ float b2f(uint16_t u) {
  __hip_bfloat16 h = *reinterpret_cast<__hip_bfloat16*>(&u);
  return __bfloat162float(h);
}
__device__ __forceinline__ void fsplit(float v, uint16_t& h, uint16_t& l) {
  h = f2b(v);
  l = f2b(v - b2f(h));
}

// ---------------- embedding gather -> split bf16: row (t*4+b)
__global__ __launch_bounds__(256) void k_embed_split(const int* __restrict__ ids,
                                                     const float* __restrict__ emb,
                                                     uint16_t* __restrict__ Hhi,
                                                     uint16_t* __restrict__ Hlo) {
  int idx = blockIdx.x * 256 + threadIdx.x;   // SEQ*BATCH*DIMX/4 float4s
  int d4 = idx & (DIMX / 4 - 1);
  int tb = idx >> 8;
  int t = tb >> 2, b = tb & 3;
  int id = ids[b * SEQ + t];
  float4 v = reinterpret_cast<const float4*>(emb + (size_t)id * DIMX)[d4];
  ushort4 h, l;
  fsplit(v.x, h.x, l.x); fsplit(v.y, h.y, l.y); fsplit(v.z, h.z, l.z); fsplit(v.w, h.w, l.w);
  reinterpret_cast<ushort4*>(Hhi)[idx] = h;
  reinterpret_cast<ushort4*>(Hlo)[idx] = l;
}

// ---------------- generic strided f32 row copy (row r -> (r>>2)*cs + (r&3)*bs)
__global__ __launch_bounds__(256) void k_copy_rows(const float* __restrict__ src, int s_cs, int s_bs,
                                                   float* __restrict__ dst, int d_cs, int d_bs,
                                                   int rows, int cols4) {
  int idx = blockIdx.x * 256 + threadIdx.x;
  int c4 = idx % cols4;
  int r = idx / cols4;
  if (r >= rows) return;
  const float4* s = reinterpret_cast<const float4*>(src + (size_t)(r >> 2) * s_cs + (size_t)(r & 3) * s_bs);
  float4* d = reinterpret_cast<float4*>(dst + (size_t)(r >> 2) * d_cs + (size_t)(r & 3) * d_bs);
  d[c4] = s[c4];
}

// ---------------- strided f32 -> split bf16 copy
__global__ __launch_bounds__(256) void k_split_rows(const float* __restrict__ src, int s_cs, int s_bs,
                                                    uint16_t* __restrict__ hi, uint16_t* __restrict__ lo,
                                                    int d_cs, int d_bs, int rows, int cols4) {
  int idx = blockIdx.x * 256 + threadIdx.x;
  int c4 = idx % cols4;
  int r = idx / cols4;
  if (r >= rows) return;
  float4 v = reinterpret_cast<const float4*>(src + (size_t)(r >> 2) * s_cs + (size_t)(r & 3) * s_bs)[c4];
  ushort4 h, l;
  fsplit(v.x, h.x, l.x); fsplit(v.y, h.y, l.y); fsplit(v.z, h.z, l.z); fsplit(v.w, h.w, l.w);
  size_t doff = (size_t)(r >> 2) * d_cs + (size_t)(r & 3) * d_bs;
  reinterpret_cast<ushort4*>(hi + doff)[c4] = h;
  reinterpret_cast<ushort4*>(lo + doff)[c4] = l;
}

// ---------------- 64x64-tile f32 transpose with split-bf16 output (for squarings)
__global__ __launch_bounds__(256) void k_transpose_split(const float* __restrict__ src,
                                                         uint16_t* __restrict__ hi,
                                                         uint16_t* __restrict__ lo) {
  __shared__ float t[64][65];
  int i0 = blockIdx.y * 64, j0 = blockIdx.x * 64;
  int c4 = (threadIdx.x & 15) * 4, rr = threadIdx.x >> 4;
#pragma unroll
  for (int p = 0; p < 4; ++p) {
    int r = rr + p * 16;
    float4 v = *reinterpret_cast<const float4*>(src + (size_t)(i0 + r) * DIMX + j0 + c4);
    t[r][c4] = v.x; t[r][c4 + 1] = v.y; t[r][c4 + 2] = v.z; t[r][c4 + 3] = v.w;
  }
  __syncthreads();
#pragma unroll
  for (int p = 0; p < 4; ++p) {
    int j = rr + p * 16;
    ushort4 h, l;
    fsplit(t[c4 + 0][j], h.x, l.x);
    fsplit(t[c4 + 1][j], h.y, l.y);
    fsplit(t[c4 + 2][j], h.z, l.z);
    fsplit(t[c4 + 3][j], h.w, l.w);
    size_t o = (size_t)(j0 + j) * DIMX + i0 + c4;
    *reinterpret_cast<ushort4*>(hi + o) = h;
    *reinterpret_cast<ushort4*>(lo + o) = l;
  }
}

// ---------------- split-bf16 MFMA GEMM (NT): out[m][n] = sum_k A[m][k]*B[n][k] (+ADD)
// A = Ahi+Alo, B = Bhi+Blo (3 MFMA products, f32 accumulate).
// Row m offset for A/ADD/O1f/O1split/O2split: (m>>2)*cs + (m&3)*bs. B dense [n][ldb].
// O1f (optional): f32 out = dot+ADD. O1hi/lo (optional): split(dot+ADD) written for
// cols n>=split_n0 at col (n-split_n0). O2hi/lo (optional): split(dot).
template <int BM, int BN>
__global__ __launch_bounds__(256) void k_mfma(
    int K,
    const uint16_t* __restrict__ Ahi, const uint16_t* __restrict__ Alo, int a_cs, int a_bs,
    const uint16_t* __restrict__ Bhi, const uint16_t* __restrict__ Blo, int ldb,
    const float* __restrict__ ADD, int add_cs, int add_bs,
    float* __restrict__ O1f, int o1_cs, int o1_bs,
    uint16_t* __restrict__ O1hi, uint16_t* __restrict__ O1lo, int o1s_cs, int o1s_bs, int split_n0,
    uint16_t* __restrict__ O2hi, uint16_t* __restrict__ O2lo, int o2_cs, int o2_bs) {
  constexpr int FM = BM / 32;   // 16x16 frags per wave (M)
  constexpr int FN = BN / 32;
  __shared__ uint16_t sAh[BM * 32], sAl[BM * 32], sBh[BN * 32], sBl[BN * 32];
  int tid = threadIdx.x;
  int lane = tid & 63;
  int wave = tid >> 6;
  int wm = wave >> 1, wn = wave & 1;
  int m0 = blockIdx.y * BM, n0 = blockIdx.x * BN;
  f32x4v acc[FM][FN] = {};
  for (int kt = 0; kt < K; kt += 32) {
    __syncthreads();
#pragma unroll
    for (int q = 0; q < BM / 64; ++q) {
      int off = q * 4096 + tid * 16;           // byte offset in 8KB/4KB tile
      int r = off >> 6;                        // tile row (64B per row)
      int cu = (off & 63) >> 1;                // col in ushorts
      size_t goff = (size_t)(m0 / 4 + (r >> 2)) * a_cs + (size_t)(r & 3) * a_bs + kt + cu;
      __builtin_amdgcn_global_load_lds(
          (const __attribute__((address_space(1))) uint32_t*)(Ahi + goff),
          (__attribute__((address_space(3))) uint32_t*)((char*)sAh + off), 16, 0, 0);
      __builtin_amdgcn_global_load_lds(
          (const __attribute__((address_space(1))) uint32_t*)(Alo + goff),
          (__attribute__((address_space(3))) uint32_t*)((char*)sAl + off), 16, 0, 0);
    }
#pragma unroll
    for (int q = 0; q < BN / 64; ++q) {
      int off = q * 4096 + tid * 16;
      int r = off >> 6, cu = (off & 63) >> 1;
      size_t goff = (size_t)(n0 + r) * ldb + kt + cu;
      __builtin_amdgcn_global_load_lds(
          (const __attribute__((address_space(1))) uint32_t*)(Bhi + goff),
          (__attribute__((address_space(3))) uint32_t*)((char*)sBh + off), 16, 0, 0);
      __builtin_amdgcn_global_load_lds(
          (const __attribute__((address_space(1))) uint32_t*)(Blo + goff),
          (__attribute__((address_space(3))) uint32_t*)((char*)sBl + off), 16, 0, 0);
    }
    __syncthreads();
    int rsel = lane & 15, ko = (lane >> 4) * 8;
    bf16x8 ah[FM], al[FM], bh[FN], bl[FN];
#pragma unroll
    for (int mf = 0; mf < FM; ++mf) {
      int row = wm * (FM * 16) + mf * 16 + rsel;
      ah[mf] = *reinterpret_cast<const bf16x8*>(sAh + row * 32 + ko);
      al[mf] = *reinterpret_cast<const bf16x8*>(sAl + row * 32 + ko);
    }
#pragma unroll
    for (int nf = 0; nf < FN; ++nf) {
      int row = wn * (FN * 16) + nf * 16 + rsel;
      bh[nf] = *reinterpret_cast<const bf16x8*>(sBh + row * 32 + ko);
      bl[nf] = *reinterpret_cast<const bf16x8*>(sBl + row * 32 + ko);
    }
#pragma unroll
    for (int mf = 0; mf < FM; ++mf)
#pragma unroll
      for (int nf = 0; nf < FN; ++nf) {
        acc[mf][nf] = __builtin_amdgcn_mfma_f32_16x16x32_bf16(ah[mf], bh[nf], acc[mf][nf], 0, 0, 0);
        acc[mf][nf] = __builtin_amdgcn_mfma_f32_16x16x32_bf16(ah[mf], bl[nf], acc[mf][nf], 0, 0, 0);
        acc[mf][nf] = __builtin_amdgcn_mfma_f32_16x16x32_bf16(al[mf], bh[nf], acc[mf][nf], 0, 0, 0);
      }
  }
  int rowg = (lane >> 4) * 4, colg = lane & 15;
#pragma unroll
  for (int mf = 0; mf < FM; ++mf)
#pragma unroll
    for (int nf = 0; nf < FN; ++nf)
#pragma unroll
      for (int r = 0; r < 4; ++r) {
        int m = m0 + wm * (FM * 16) + mf * 16 + rowg + r;
        int n = n0 + wn * (FN * 16) + nf * 16 + colg;
        size_t ro = (size_t)(m >> 2);
        float dot = acc[mf][nf][r];
        float v = dot;
        if (ADD) v += ADD[ro * add_cs + (size_t)(m & 3) * add_bs + n];
        if (O1f) O1f[ro * o1_cs + (size_t)(m & 3) * o1_bs + n] = v;
        if (O1hi && n >= split_n0) {
          uint16_t h, l;
          fsplit(v, h, l);
          size_t o = ro * o1s_cs + (size_t)(m & 3) * o1s_bs + (n - split_n0);
          O1hi[o] = h; O1lo[o] = l;
        }
        if (O2hi) {
          uint16_t h, l;
          fsplit(dot, h, l);
          size_t o = ro * o2_cs + (size_t)(m & 3) * o2_bs + n;
          O2hi[o] = h; O2lo[o] = l;
        }
      }
}

// ---------------- fp32 GEMM, 32x32 tile (phase-2 small scan steps)
template <bool NT>
__global__ __launch_bounds__(256) void k_gemm32(
    int M, int N, int K,
    const float* __restrict__ Ab, int a_cs, int a_bs,
    const float* __restrict__ Bb, int ldb,
    const float* __restrict__ ADDb, int add_cs, int add_bs,
    float* __restrict__ O1, int o1_cs, int o1_bs,
    float* __restrict__ O2, int o2_cs, int o2_bs) {
  __shared__ float As[16][36];
  __shared__ float Bs[16][36];
  int tid = threadIdx.x;
  int n0 = blockIdx.x * 32, m0 = blockIdx.y * 32;
  int tx = tid & 15, ty = tid >> 4;
  float acc[2][2] = {};
  for (int kt = 0; kt < K; kt += 16) {
    {
      int mm = tid >> 3, kc = (tid & 7) * 2;
      int m = m0 + mm;
      float2 av = make_float2(0.f, 0.f);
      if (m < M) av = *reinterpret_cast<const float2*>(Ab + (size_t)(m >> 2) * a_cs + (size_t)(m & 3) * a_bs + kt + kc);
      As[kc + 0][mm] = av.x; As[kc + 1][mm] = av.y;
      if (NT) {
        int n = n0 + mm;
        float2 bv = *reinterpret_cast<const float2*>(Bb + (size_t)n * ldb + kt + kc);
        Bs[kc + 0][mm] = bv.x; Bs[kc + 1][mm] = bv.y;
      } else {
        int kk = tid >> 4, nc = (tid & 15) * 2;
        float2 bv = *reinterpret_cast<const float2*>(Bb + (size_t)(kt + kk) * ldb + n0 + nc);
        *reinterpret_cast<float2*>(&Bs[kk][nc]) = bv;
      }
    }
    __syncthreads();
#pragma unroll
    for (int kk = 0; kk < 16; ++kk) {
      float2 a = *reinterpret_cast<const float2*>(&As[kk][ty * 2]);
      float2 b = *reinterpret_cast<const float2*>(&Bs[kk][tx * 2]);
      acc[0][0] = fmaf(a.x, b.x, acc[0][0]);
      acc[0][1] = fmaf(a.x, b.y, acc[0][1]);
      acc[1][0] = fmaf(a.y, b.x, acc[1][0]);
      acc[1][1] = fmaf(a.y, b.y, acc[1][1]);
    }
    __syncthreads();
  }
#pragma unroll
  for (int i = 0; i < 2; ++i) {
    int m = m0 + ty * 2 + i;
    if (m >= M) continue;
#pragma unroll
    for (int j = 0; j < 2; ++j) {
      int n = n0 + tx * 2 + j;
      float dot = acc[i][j];
      float v = dot;
      if (ADDb) v += ADDb[(size_t)(m >> 2) * add_cs + (size_t)(m & 3) * add_bs + n];
      O1[(size_t)(m >> 2) * o1_cs + (size_t)(m & 3) * o1_bs + n] = v;
      if (O2) O2[(size_t)(m >> 2) * o2_cs + (size_t)(m & 3) * o2_bs + n] = dot;
    }
  }
}

// ---------------- reorder H_hi [t][b][d] -> Y [b][t][d] (logits A operand)
__global__ __launch_bounds__(256) void k_reorder_hi(const uint16_t* __restrict__ Hhi, uint16_t* __restrict__ Y) {
  int idx = blockIdx.x * 256 + threadIdx.x;   // SEQ*BATCH*DIMX/4
  int d4 = idx & (DIMX / 4 - 1);
  int tb = idx >> 8;
  int t = tb >> 2, b = tb & 3;
  ushort4 v = reinterpret_cast<const ushort4*>(Hhi)[idx];
  reinterpret_cast<ushort4*>(Y + (size_t)(b * SEQ + t) * DIMX)[d4] = v;
}

__global__ __launch_bounds__(256) void k_cast_w(const float* __restrict__ src, uint16_t* __restrict__ dst, int n4) {
  int idx = blockIdx.x * 256 + threadIdx.x;
  if (idx >= n4) return;
  float4 v = reinterpret_cast<const float4*>(src)[idx];
  ushort4 o;
  o.x = f2b(v.x); o.y = f2b(v.y); o.z = f2b(v.z); o.w = f2b(v.w);
  reinterpret_cast<ushort4*>(dst)[idx] = o;
}

// ---------------- logits GEMM: bf16 MFMA 128x128 (unchanged from round 1)
__global__ __launch_bounds__(256) void k_logits(const uint16_t* __restrict__ A,
                                                const uint16_t* __restrict__ Bt,
                                                float* __restrict__ C) {
  __shared__ uint16_t As[128 * 32];
  __shared__ uint16_t Bs[128 * 32];
  int tid = threadIdx.x;
  int bx = blockIdx.x, by = blockIdx.y;
  int lane = tid & 63, wave = tid >> 6;
  int wm = wave >> 1, wn = wave & 1;
  f32x4v acc[4][4] = {};
  const uint16_t* Ag = A + (size_t)by * 128 * 1024;
  const uint16_t* Bg = Bt + (size_t)bx * 128 * 1024;
  for (int kt = 0; kt < 1024; kt += 32) {
    __syncthreads();
#pragma unroll
    for (int q = 0; q < 2; ++q) {
      int off = q * 4096 + tid * 16;
      int r = off >> 6, cu = (off & 63) >> 1;
      __builtin_amdgcn_global_load_lds(
          (const __attribute__((address_space(1))) uint32_t*)(Ag + (size_t)r * 1024 + kt + cu),
          (__attribute__((address_space(3))) uint32_t*)((char*)As + off), 16, 0, 0);
      __builtin_amdgcn_global_load_lds(
          (const __attribute__((address_space(1))) uint32_t*)(Bg + (size_t)r * 1024 + kt + cu),
          (__attribute__((address_space(3))) uint32_t*)((char*)Bs + off), 16, 0, 0);
    }
    __syncthreads();
    int rsel = lane & 15, ko = (lane >> 4) * 8;
    bf16x8 af[4], bfr[4];
#pragma unroll
    for (int mf = 0; mf < 4; ++mf)
      af[mf] = *reinterpret_cast<const bf16x8*>(As + (wm * 64 + mf * 16 + rsel) * 32 + ko);
#pragma unroll
    for (int nf = 0; nf < 4; ++nf)
      bfr[nf] = *reinterpret_cast<const bf16x8*>(Bs + (wn * 64 + nf * 16 + rsel) * 32 + ko);
#pragma unroll
    for (int mf = 0; mf < 4; ++mf)
#pragma unroll
      for (int nf = 0; nf < 4; ++nf)
        acc[mf][nf] = __builtin_amdgcn_mfma_f32_16x16x32_bf16(af[mf], bfr[nf], acc[mf][nf], 0, 0, 0);
  }
  int rowg = (lane >> 4) * 4;
  int colg = lane & 15;
#pragma unroll
  for (int mf = 0; mf < 4; ++mf)
#pragma unroll
    for (int nf = 0; nf < 4; ++nf)
#pragma unroll
      for (int r = 0; r < 4; ++r) {
        int m = by * 128 + wm * 64 + mf * 16 + rowg + r;
        int n = bx * 128 + wn * 64 + nf * 16 + colg;
        C[(size_t)m * VOCAB + n] = acc[mf][nf][r];
      }
}

// =========================================================================
extern "C" void kernel_launch(void* const* d_in, const int* in_sizes, int n_in,
                              void* d_out, int out_size, void* d_ws, size_t ws_size,
                              hipStream_t stream) {
  const int* ids = (const int*)d_in[0];
  const float* emb = (const float*)d_in[1];
  const float* W = (const float*)d_in[2];
  const float* outw = (const float*)d_in[3];
  const float* starter = (const float*)d_in[4];
  float* out = (float*)d_out;

  char* wsb = (char*)d_ws;
  size_t off = 0;
  auto alloc = [&](size_t bytes) {
    void* p = wsb + off;
    off = (off + bytes + 255) & ~(size_t)255;
    return p;
  };
  const size_t TB = SEQ * BATCH;  // 4096 rows
  // split H ping-pong
  uint16_t* Hhi[2] = {(uint16_t*)alloc(TB * DIMX * 2), (uint16_t*)alloc(TB * DIMX * 2)};
  uint16_t* Hlo[2] = {(uint16_t*)alloc(TB * DIMX * 2), (uint16_t*)alloc(TB * DIMX * 2)};
  float* P = (float*)alloc(TB * 2 * DIMX * 4);            // [t][b][a|u] f32
  uint16_t* PUhi = (uint16_t*)alloc(TB * DIMX * 2);       // split of scan value l
  uint16_t* PUlo = (uint16_t*)alloc(TB * DIMX * 2);
  uint16_t* Shi = (uint16_t*)alloc(TB * DIMX * 2);        // split of s_{t-1}
  uint16_t* Slo = (uint16_t*)alloc(TB * DIMX * 2);
  float* LAM = (float*)alloc((size_t)CCH * BATCH * DIMX * 4);
  float* SIGB = (float*)alloc((size_t)(CC2 + 1) * BATCH * DIMX * 4);
  float* SIG = (float*)alloc((size_t)CCH * BATCH * DIMX * 4);
  float* G2a = (float*)alloc((size_t)CC2 * BATCH * DIMX * 4);
  float* G2b = (float*)alloc((size_t)CC2 * BATCH * DIMX * 4);
  uint16_t* Ghi[2] = {(uint16_t*)alloc((size_t)CCH * BATCH * DIMX * 2), (uint16_t*)alloc((size_t)CCH * BATCH * DIMX * 2)};
  uint16_t* Glo[2] = {(uint16_t*)alloc((size_t)CCH * BATCH * DIMX * 2), (uint16_t*)alloc((size_t)CCH * BATCH * DIMX * 2)};
  float* Ass = (float*)alloc((size_t)DIMX * DIMX * 4);
  float* PWf[2] = {(float*)alloc((size_t)DIMX * DIMX * 4), (float*)alloc((size_t)DIMX * DIMX * 4)};
  float* A16f = (float*)alloc((size_t)DIMX * DIMX * 4);
  float* A128f = (float*)alloc((size_t)DIMX * DIMX * 4);
  uint16_t* P0hi = (uint16_t*)alloc((size_t)DIMX * DIMX * 2);
  uint16_t* P0lo = (uint16_t*)alloc((size_t)DIMX * DIMX * 2);
  uint16_t* PWhi[2] = {(uint16_t*)alloc((size_t)DIMX * DIMX * 2), (uint16_t*)alloc((size_t)DIMX * DIMX * 2)};
  uint16_t* PWlo[2] = {(uint16_t*)alloc((size_t)DIMX * DIMX * 2), (uint16_t*)alloc((size_t)DIMX * DIMX * 2)};
  uint16_t* Thi = (uint16_t*)alloc((size_t)DIMX * DIMX * 2);
  uint16_t* Tlo = (uint16_t*)alloc((size_t)DIMX * DIMX * 2);
  uint16_t* W1hi = (uint16_t*)alloc((size_t)2 * DIMX * DIMX * 2);
  uint16_t* W1lo = (uint16_t*)alloc((size_t)2 * DIMX * DIMX * 2);
  uint16_t* WShi = (uint16_t*)alloc((size_t)DIMX * DIMX * 2);
  uint16_t* WSlo = (uint16_t*)alloc((size_t)DIMX * DIMX * 2);
  uint16_t* YSB = (uint16_t*)alloc(TB * DIMX * 2);
  uint16_t* OWB = (uint16_t*)alloc((size_t)VOCAB * DIMX * 2);

  k_embed_split<<<TB * DIMX / 4 / 256, 256, 0, stream>>>(ids, emb, Hhi[0], Hlo[0]);

  int cur = 0;
  for (int l = 0; l < NLAYERS; ++l) {
    const float* Wl = W + (size_t)l * 2 * DIMX * 2 * DIMX;

    // split-cast W[:,0:1024] (2048 rows) and W_hs = W[0:1024, 1024:2048]
    k_split_rows<<<2 * DIMX * DIMX / 4 / 256, 256, 0, stream>>>(
        Wl, 4 * 2 * DIMX, 2 * DIMX, W1hi, W1lo, 4 * DIMX, DIMX, 2 * DIMX, DIMX / 4);
    k_split_rows<<<DIMX * DIMX / 4 / 256, 256, 0, stream>>>(
        Wl + DIMX, 4 * 2 * DIMX, 2 * DIMX, WShi, WSlo, 4 * DIMX, DIMX, DIMX, DIMX / 4);

    // [a|u] = H @ W[:,0:1024]^T ; f32 -> P, split(u) -> PU
    k_mfma<128, 128><<<dim3(2 * DIMX / 128, TB / 128), 256, 0, stream>>>(
        DIMX,
        Hhi[cur], Hlo[cur], 4 * DIMX, DIMX,
        W1hi, W1lo, DIMX,
        nullptr, 0, 0,
        P, 4 * 2 * DIMX, 2 * DIMX,
        PUhi, PUlo, 4 * DIMX, DIMX, DIMX,
        nullptr, nullptr, 0, 0);

    // W_ss dense copy + split
    k_copy_rows<<<DIMX * DIMX / 4 / 256, 256, 0, stream>>>(
        Wl + (size_t)DIMX * 2 * DIMX + DIMX, 4 * 2 * DIMX, 2 * DIMX,
        Ass, 4 * DIMX, DIMX, DIMX, DIMX / 4);
    k_split_rows<<<DIMX * DIMX / 4 / 256, 256, 0, stream>>>(
        Ass, 4 * DIMX, DIMX, P0hi, P0lo, 4 * DIMX, DIMX, DIMX, DIMX / 4);

    // power chain A^(2^k), k=1..7 (A^16 -> A16f, A^128 -> A128f)
    {
      float* curf = Ass;
      uint16_t *curh = P0hi, *curl = P0lo;
      for (int k = 1; k <= 7; ++k) {
        k_transpose_split<<<dim3(16, 16), 256, 0, stream>>>(curf, Thi, Tlo);
        float* of = (k == 4) ? A16f : (k == 7) ? A128f : PWf[k & 1];
        uint16_t* oh = (k == 7) ? nullptr : PWhi[k & 1];
        uint16_t* ol = (k == 7) ? nullptr : PWlo[k & 1];
        k_mfma<128, 128><<<dim3(8, 8), 256, 0, stream>>>(
            DIMX,
            curh, curl, 4 * DIMX, DIMX,
            Thi, Tlo, DIMX,
            nullptr, 0, 0,
            of, 4 * DIMX, DIMX,
            oh, ol, 4 * DIMX, DIMX, 0,
            nullptr, nullptr, 0, 0);
        curf = of; curh = oh; curl = ol;
      }
    }

    // phase 1: local scans l_j = A l_{j-1} + u_j (M=256 rows = (chunk,b))
    for (int j = 1; j < TCH; ++j) {
      k_mfma<64, 64><<<dim3(DIMX / 64, CCH * BATCH / 64), 256, 0, stream>>>(
          DIMX,
          PUhi + (size_t)(j - 1) * BATCH * DIMX, PUlo + (size_t)(j - 1) * BATCH * DIMX,
          TCH * BATCH * DIMX, DIMX,
          P0hi, P0lo, DIMX,
          P + DIMX + (size_t)j * BATCH * 2 * DIMX, TCH * BATCH * 2 * DIMX, 2 * DIMX,
          P + DIMX + (size_t)j * BATCH * 2 * DIMX, TCH * BATCH * 2 * DIMX, 2 * DIMX,
          PUhi + (size_t)j * BATCH * DIMX, PUlo + (size_t)j * BATCH * DIMX, TCH * BATCH * DIMX, DIMX, 0,
          nullptr, nullptr, 0, 0);
    }

    // phase 2 (two-level, fp32):
    // e_c = l_end(c) -> LAM[c][b][:]
    k_copy_rows<<<CCH * BATCH * DIMX / 4 / 256, 256, 0, stream>>>(
        P + DIMX + (size_t)(TCH - 1) * BATCH * 2 * DIMX, TCH * BATCH * 2 * DIMX, 2 * DIMX,
        LAM, 4 * DIMX, DIMX, CCH * BATCH, DIMX / 4);
    // 2a: inner local scans over groups of 8 (in place), M=32
    for (int j = 1; j < TC2; ++j) {
      k_gemm32<true><<<dim3(DIMX / 32, 1), 256, 0, stream>>>(
          CC2 * BATCH, DIMX, DIMX,
          LAM + (size_t)(j - 1) * BATCH * DIMX, TC2 * BATCH * DIMX, DIMX,
          A16f, DIMX,
          LAM + (size_t)j * BATCH * DIMX, TC2 * BATCH * DIMX, DIMX,
          LAM + (size_t)j * BATCH * DIMX, TC2 * BATCH * DIMX, DIMX,
          nullptr, 0, 0);
    }
    // 2b: beta chain, M=4: beta_{g+1} = A128 beta_g + LAM[8g+7]
    k_copy_rows<<<BATCH * DIMX / 4 / 256, 256, 0, stream>>>(
        starter + (size_t)l * DIMX, 0, 0, SIGB, 4 * DIMX, DIMX, BATCH, DIMX / 4);
    for (int g = 0; g < CC2; ++g) {
      k_gemm32<true><<<dim3(DIMX / 32, 1), 256, 0, stream>>>(
          BATCH, DIMX, DIMX,
          SIGB + (size_t)g * BATCH * DIMX, 4 * DIMX, DIMX,
          A128f, DIMX,
          LAM + ((size_t)g * TC2 + TC2 - 1) * BATCH * DIMX, 0, DIMX,
          SIGB + (size_t)(g + 1) * BATCH * DIMX, 4 * DIMX, DIMX,
          nullptr, 0, 0);
    }
    // 2c: sigma_{8g} = beta_g; sigma_{8g+j} = A16^j beta_g + LAM[8g+j-1]
    k_copy_rows<<<CC2 * BATCH * DIMX / 4 / 256, 256, 0, stream>>>(
        SIGB, 4 * DIMX, DIMX, G2a, 4 * DIMX, DIMX, CC2 * BATCH, DIMX / 4);
    k_copy_rows<<<CC2 * BATCH * DIMX / 4 / 256, 256, 0, stream>>>(
        SIGB, 4 * DIMX, DIMX, SIG, TC2 * BATCH * DIMX, DIMX, CC2 * BATCH, DIMX / 4);
    {
      float* gp = G2a; float* gq = G2b;
      for (int j = 1; j < TC2; ++j) {
        k_gemm32<true><<<dim3(DIMX / 32, 1), 256, 0, stream>>>(
            CC2 * BATCH, DIMX, DIMX,
            gp, 4 * DIMX, DIMX,
            A16f, DIMX,
            LAM + (size_t)(j - 1) * BATCH * DIMX, TC2 * BATCH * DIMX, DIMX,
            SIG + (size_t)j * BATCH * DIMX, TC2 * BATCH * DIMX, DIMX,
            gq, 4 * DIMX, DIMX);
        float* t = gp; gp = gq; gq = t;
      }
    }
    // split sigma into G (phase-3 A-op) and S positions t=c*16
    k_split_rows<<<CCH * BATCH * DIMX / 4 / 256, 256, 0, stream>>>(
        SIG, 4 * DIMX, DIMX, Ghi[0], Glo[0], 4 * DIMX, DIMX, CCH * BATCH, DIMX / 4);
    k_split_rows<<<CCH * BATCH * DIMX / 4 / 256, 256, 0, stream>>>(
        SIG, 4 * DIMX, DIMX, Shi, Slo, TCH * BATCH * DIMX, DIMX, CCH * BATCH, DIMX / 4);

    // phase 3: G_j = A G_{j-1}; S[cT+j] = split(G_j + l_{cT+j-1})
    {
      int gp = 0;
      for (int j = 1; j < TCH; ++j) {
        k_mfma<64, 64><<<dim3(DIMX / 64, CCH * BATCH / 64), 256, 0, stream>>>(
            DIMX,
            Ghi[gp], Glo[gp], 4 * DIMX, DIMX,
            P0hi, P0lo, DIMX,
            P + DIMX + (size_t)(j - 1) * BATCH * 2 * DIMX, TCH * BATCH * 2 * DIMX, 2 * DIMX,
            nullptr, 0, 0,
            Shi + (size_t)j * BATCH * DIMX, Slo + (size_t)j * BATCH * DIMX, TCH * BATCH * DIMX, DIMX, 0,
            Ghi[gp ^ 1], Glo[gp ^ 1], 4 * DIMX, DIMX);
        gp ^= 1;
      }
    }

    // H_next = a + S @ W_hs^T  (split out only)
    k_mfma<128, 128><<<dim3(DIMX / 128, TB / 128), 256, 0, stream>>>(
        DIMX,
        Shi, Slo, 4 * DIMX, DIMX,
        WShi, WSlo, DIMX,
        P, 2 * 4 * DIMX, 2 * DIMX,
        nullptr, 0, 0,
        Hhi[cur ^ 1], Hlo[cur ^ 1], 4 * DIMX, DIMX, 0,
        nullptr, nullptr, 0, 0);
    cur ^= 1;
  }

  // logits
  k_reorder_hi<<<TB * DIMX / 4 / 256, 256, 0, stream>>>(Hhi[cur], YSB);
  k_cast_w<<<(int)((size_t)VOCAB * DIMX / 4 / 256), 256, 0, stream>>>(outw, OWB, VOCAB * DIMX / 4);
  k_logits<<<dim3(VOCAB / 128, TB / 128), 256, 0, stream>>>(YSB, OWB, out);
}